// Round 4
// baseline (1669.964 us; speedup 1.0000x reference)
//
#include <hip/hip_runtime.h>
#include <hip/hip_bf16.h>

#define NTOK 8192
#define DM 1024
#define NE 8
#define DH 2048
#define CAP 18432   // 16384 + 8*256 padding, multiple of 256 (tiles must not span experts)

typedef __attribute__((ext_vector_type(8))) short short8;
typedef __attribute__((ext_vector_type(4))) float float4v;

// async global->LDS DMA, 16B per lane; LDS dest is wave-uniform base + lane*16
#define ASYNC_COPY16(gsrc, ldst)                                                              \
    __builtin_amdgcn_global_load_lds((const __attribute__((address_space(1))) unsigned int*)(gsrc), \
                                     (__attribute__((address_space(3))) unsigned int*)(ldst), \
                                     16, 0, 0)

static __device__ __forceinline__ unsigned short f2bf(float f) {
    __hip_bfloat16 h = __float2bfloat16(f);
    return *reinterpret_cast<unsigned short*>(&h);
}

// branch-free gelu, exact-erf form via Abramowitz-Stegun 7.1.26 (|err| < 1.5e-7)
static __device__ __forceinline__ float fast_gelu(float v) {
    float x = v * 0.70710678118654752f;
    float ax = fabsf(x);
    float t = __frcp_rn(1.0f + 0.3275911f * ax);
    float poly = ((((1.061405429f * t - 1.453152027f) * t + 1.421413741f) * t
                   - 0.284496736f) * t + 0.254829592f) * t;
    float y = 1.0f - poly * __expf(-ax * ax);   // erf(|x|)
    float erfv = copysignf(y, x);
    return 0.5f * v * (1.0f + erfv);
}

// ---------------- weight transpose: src [z][R][C] fp32 -> dst [z][C][R] bf16 ----------------

__global__ __launch_bounds__(256) void k_transpose(const float* __restrict__ src,
                                                   __hip_bfloat16* __restrict__ dst,
                                                   int R, int C) {
    __shared__ float t[64][65];
    size_t mat = (size_t)blockIdx.z * R * C;
    src += mat;
    dst += mat;
    int c0 = blockIdx.x * 64, r0 = blockIdx.y * 64;
    int tx = threadIdx.x & 63, ty = threadIdx.x >> 6;  // 64 x 4
#pragma unroll
    for (int i = 0; i < 16; i++) {
        int r = ty + i * 4;
        t[r][tx] = src[(size_t)(r0 + r) * C + c0 + tx];
    }
    __syncthreads();
    int rx = (threadIdx.x & 15) * 4;  // 0..60
    int cy = threadIdx.x >> 4;        // 0..15
#pragma unroll
    for (int i = 0; i < 4; i++) {
        int c = cy + i * 16;
        ushort4 v;
        v.x = f2bf(t[rx + 0][c]);
        v.y = f2bf(t[rx + 1][c]);
        v.z = f2bf(t[rx + 2][c]);
        v.w = f2bf(t[rx + 3][c]);
        *(ushort4*)((unsigned short*)dst + (size_t)(c0 + c) * R + r0 + rx) = v;
    }
}

// ---------------- router (atomic-free; also emits xb = bf16(x)) ----------------

__global__ __launch_bounds__(256) void k_router(const float* __restrict__ x,
                                                const float* __restrict__ rw,
                                                const float* __restrict__ rb,
                                                __hip_bfloat16* __restrict__ xb,
                                                int* __restrict__ topidx,
                                                float* __restrict__ topw,
                                                float* __restrict__ probs8,   // [NTOK][8]
                                                float* __restrict__ zent) {   // [NTOK][2]
    int lane = threadIdx.x & 63, wv = threadIdx.x >> 6;
    int n = blockIdx.x * 4 + wv;
    const float* xr = x + (size_t)n * DM;
    unsigned short* xbr = (unsigned short*)xb + (size_t)n * DM;
    float p[8] = {0.f, 0.f, 0.f, 0.f, 0.f, 0.f, 0.f, 0.f};
#pragma unroll
    for (int i = 0; i < 16; i++) {
        int d = lane + i * 64;
        float xv = xr[d];
        xbr[d] = f2bf(xv);
        const float4* w4 = (const float4*)(rw + (size_t)d * 8);
        float4 wa = w4[0], wb = w4[1];
        p[0] += xv * wa.x; p[1] += xv * wa.y; p[2] += xv * wa.z; p[3] += xv * wa.w;
        p[4] += xv * wb.x; p[5] += xv * wb.y; p[6] += xv * wb.z; p[7] += xv * wb.w;
    }
#pragma unroll
    for (int e = 0; e < 8; e++) {
#pragma unroll
        for (int off = 32; off > 0; off >>= 1) p[e] += __shfl_down(p[e], off);
    }
    if (lane == 0) {
        float logits[8], probs[8];
        float mx = -1e30f;
#pragma unroll
        for (int e = 0; e < 8; e++) {
            logits[e] = p[e] + rb[e];
            mx = fmaxf(mx, logits[e]);
        }
        float se = 0.f;
#pragma unroll
        for (int e = 0; e < 8; e++) {
            probs[e] = __expf(logits[e] - mx);
            se += probs[e];
        }
        float inv = 1.f / se;
        float z = mx + logf(se);
        float ent = 0.f;
#pragma unroll
        for (int e = 0; e < 8; e++) {
            probs[e] *= inv;
            ent -= probs[e] * logf(probs[e] + 1e-10f);
        }
        int i0 = 0;
#pragma unroll
        for (int e = 1; e < 8; e++)
            if (probs[e] > probs[i0]) i0 = e;
        int i1 = (i0 == 0) ? 1 : 0;
#pragma unroll
        for (int e = 0; e < 8; e++)
            if (e != i0 && e != i1 && probs[e] > probs[i1]) i1 = e;
        float w0 = probs[i0], w1v = probs[i1];
        float s = w0 + w1v + 1e-9f;
        topidx[2 * n] = i0;
        topidx[2 * n + 1] = i1;
        topw[2 * n] = w0 / s;
        topw[2 * n + 1] = w1v / s;
        float* pr = probs8 + (size_t)n * 8;
#pragma unroll
        for (int e = 0; e < 8; e++) pr[e] = probs[e];
        zent[2 * n] = z * z;
        zent[2 * n + 1] = ent;
    }
}

// ---------------- stats reduction ----------------

__global__ __launch_bounds__(256) void k_stats(const int* __restrict__ topidx,
                                               const float* __restrict__ probs8,
                                               const float* __restrict__ zent,
                                               float* __restrict__ fcnt,
                                               float* __restrict__ sump,
                                               float* __restrict__ szent) {
    int n = blockIdx.x * 256 + threadIdx.x;
    float v[18];
    int e0 = topidx[2 * n], e1 = topidx[2 * n + 1];
#pragma unroll
    for (int e = 0; e < 8; e++) v[e] = (float)((e == e0) + (e == e1));
    const float4* p4 = (const float4*)(probs8 + (size_t)n * 8);
    float4 pa = p4[0], pb = p4[1];
    v[8] = pa.x; v[9] = pa.y; v[10] = pa.z; v[11] = pa.w;
    v[12] = pb.x; v[13] = pb.y; v[14] = pb.z; v[15] = pb.w;
    v[16] = zent[2 * n];
    v[17] = zent[2 * n + 1];
#pragma unroll
    for (int i = 0; i < 18; i++)
#pragma unroll
        for (int off = 32; off > 0; off >>= 1) v[i] += __shfl_down(v[i], off);
    __shared__ float part[4][18];
    int lane = threadIdx.x & 63, wv = threadIdx.x >> 6;
    if (lane == 0)
#pragma unroll
        for (int i = 0; i < 18; i++) part[wv][i] = v[i];
    __syncthreads();
    if (threadIdx.x == 0) {
#pragma unroll
        for (int i = 0; i < 18; i++) {
            float s = part[0][i] + part[1][i] + part[2][i] + part[3][i];
            if (i < 8) atomicAdd(&fcnt[i], s);
            else if (i < 16) atomicAdd(&sump[i - 8], s);
            else atomicAdd(&szent[i - 16], s);
        }
    }
}

// ---------------- scan + scatter ----------------

__global__ void k_scan(const float* __restrict__ fcnt, int* __restrict__ offs) {
    if (threadIdx.x == 0 && blockIdx.x == 0) {
        int o = 0;
        for (int e = 0; e < NE; e++) {
            offs[e] = o;
            int c = (int)(fcnt[e] + 0.5f);
            o += (c + 255) & ~255;   // align 256: GEMM row-tiles (256 rows) never span experts
        }
        offs[NE] = o;
    }
}

__global__ __launch_bounds__(256) void k_scatter(const int* __restrict__ topidx,
                                                 const float* __restrict__ topw,
                                                 const int* __restrict__ offs,
                                                 int* __restrict__ cnt2,
                                                 int* __restrict__ rowtok,
                                                 float* __restrict__ roww,
                                                 int* __restrict__ slot) {
    __shared__ int lcnt[8], lbase[8];
    int tid = threadIdx.x;
    if (tid < 8) lcnt[tid] = 0;
    __syncthreads();
    int n = blockIdx.x * 256 + tid;
    int e0 = topidx[2 * n], e1 = topidx[2 * n + 1];
    int p0 = atomicAdd(&lcnt[e0], 1);
    int p1 = atomicAdd(&lcnt[e1], 1);
    __syncthreads();
    if (tid < 8) lbase[tid] = atomicAdd(&cnt2[tid], lcnt[tid]);
    __syncthreads();
    int r0 = offs[e0] + lbase[e0] + p0;
    int r1 = offs[e1] + lbase[e1] + p1;
    rowtok[r0] = n; roww[r0] = topw[2 * n];     slot[2 * n] = r0;
    rowtok[r1] = n; roww[r1] = topw[2 * n + 1]; slot[2 * n + 1] = r1;
}

// ---------------- GEMM1: hidden = gelu(x_gathered @ w1 + b1), bf16 out ----------------
// 256x128 tile, BK=32, 8 waves (4Mx2N, 64x64/wave), DOUBLE-buffered LDS 48KB ->
// 3 blocks/CU (24 waves/CU): the m97/m114 mechanism -- each block's vmcnt(0) drain
// + barrier stall is covered by the other two blocks' MFMA/LDS work. One barrier per
// K-tile; compiler interleaves the ds_read burst with the MFMA cluster via counted
// lgkmcnt (within-wave overlap).
// 16B-chunk involution swizzle phys = q ^ ((row>>1)&3): staging pre-swizzles the GLOBAL
// src (LDS dest stays linear = tid*16B), reads apply the same XOR -> 2-way banks (free).

#define KT1 (DM / 32)   // 32 K-tiles

__global__ __launch_bounds__(512, 6) void k_gemm1(const __hip_bfloat16* __restrict__ xb,
                                                  const __hip_bfloat16* __restrict__ w1T,  // [E][H][D]
                                                  const float* __restrict__ b1,            // [E][H]
                                                  const int* __restrict__ rowtok,
                                                  const int* __restrict__ offs,
                                                  __hip_bfloat16* __restrict__ hid) {      // [CAP][DH]
    // 1152 blocks = 8 XCD x (9 row-tiles x 16 col-tiles), col fastest -> A-tile L2 reuse
    int bid = blockIdx.x;
    int ib = bid >> 3;
    int row0 = ((bid & 7) * 9 + (ib >> 4)) * 256;
    if (row0 >= offs[NE]) return;
    int h0 = (ib & 15) * 128;
    int e = 0;
    while (row0 >= offs[e + 1]) e++;
    int tid = threadIdx.x;

    __shared__ __align__(16) short lds[2][12288];  // per buffer: A 16KB (256x32) | B 8KB (128x32)
    __shared__ int tokoff[256];
    if (tid < 256) {
        int t = rowtok[row0 + tid];
        tokoff[tid] = (t < 0 ? 0 : t) * DM;  // pad rows compute on token 0 (output unused)
    }
    __syncthreads();

    // staging map: thread -> (row 0..127 within half, 16B chunk)
    int sr = tid >> 2, pc = tid & 3;
    int ch = pc ^ ((sr >> 1) & 3);     // (row+128)>>1&3 == row>>1&3: same swz both halves
    const short* aS0 = (const short*)xb + tokoff[sr] + ch * 8;
    const short* aS1 = (const short*)xb + tokoff[128 + sr] + ch * 8;
    const short* bS  = (const short*)w1T + ((size_t)e * DH + h0 + sr) * DM + ch * 8;
    int ldo = sr * 32 + pc * 8;        // shorts; == tid*16B -> linear dest for global_load_lds

    int lane = tid & 63, wv = tid >> 6;
    int wm = (wv >> 1) * 64, wn = (wv & 1) * 64;   // 4M x 2N waves, 64x64 per wave
    int quad = lane >> 4, l16 = lane & 15;
    int a_off[4], b_off[4];
#pragma unroll
    for (int mt = 0; mt < 4; mt++) {
        int r = wm + mt * 16 + l16;
        a_off[mt] = r * 32 + ((quad ^ ((r >> 1) & 3)) * 8);
    }
#pragma unroll
    for (int nt = 0; nt < 4; nt++) {
        int r = wn + nt * 16 + l16;
        b_off[nt] = 8192 + r * 32 + ((quad ^ ((r >> 1) & 3)) * 8);
    }
    float4v acc[4][4];
#pragma unroll
    for (int i = 0; i < 4; i++)
#pragma unroll
        for (int j = 0; j < 4; j++) {
            float4v z = {0.f, 0.f, 0.f, 0.f};
            acc[i][j] = z;
        }

    // prologue: stage tile 0 into buffer 0, drain
    ASYNC_COPY16(aS0, &lds[0][ldo]);
    ASYNC_COPY16(aS1, &lds[0][4096 + ldo]);
    ASYNC_COPY16(bS,  &lds[0][8192 + ldo]);
    asm volatile("s_waitcnt vmcnt(0)" ::: "memory");
    asm volatile("s_barrier" ::: "memory");

    int buf = 0;
#pragma unroll 1
    for (int t = 0; t < KT1; ++t) {
        const short* Ab = &lds[buf][0];
        int k1 = (t + 1) * 32;
        if (t + 1 < KT1) {  // stage next tile into the other buffer (its reads done last iter)
            ASYNC_COPY16(aS0 + k1, &lds[buf ^ 1][ldo]);
            ASYNC_COPY16(aS1 + k1, &lds[buf ^ 1][4096 + ldo]);
            ASYNC_COPY16(bS + k1,  &lds[buf ^ 1][8192 + ldo]);
        }
        short8 af[4], bf[4];
#pragma unroll
        for (int mt = 0; mt < 4; mt++) af[mt] = *(const short8*)(Ab + a_off[mt]);
#pragma unroll
        for (int nt = 0; nt < 4; nt++) bf[nt] = *(const short8*)(Ab + b_off[nt]);
        __builtin_amdgcn_s_setprio(1);
#pragma unroll
        for (int mt = 0; mt < 4; mt++)
#pragma unroll
            for (int nt = 0; nt < 4; nt++)
                acc[mt][nt] = __builtin_amdgcn_mfma_f32_16x16x32_bf16(af[mt], bf[nt], acc[mt][nt], 0, 0, 0);
        __builtin_amdgcn_s_setprio(0);
        // next tile fully landed (all waves) before anyone reads it next iter;
        // this block's drain stall is covered by the other 2 resident blocks (m114)
        asm volatile("s_waitcnt vmcnt(0)" ::: "memory");
        asm volatile("s_barrier" ::: "memory");
        buf ^= 1;
    }

    const float* b1e = b1 + (size_t)e * DH + h0;
#pragma unroll
    for (int mt = 0; mt < 4; mt++) {
#pragma unroll
        for (int nt = 0; nt < 4; nt++) {
            int rl = wm + mt * 16 + quad * 4;
            int cl = wn + nt * 16 + l16;
            float bias = b1e[cl];
#pragma unroll
            for (int r = 0; r < 4; r++) {
                float v = fast_gelu(acc[mt][nt][r] + bias);
                hid[(size_t)(row0 + rl + r) * DH + h0 + cl] = __float2bfloat16(v);
            }
        }
    }
}

// ---------------- GEMM2: outb = (hidden @ w2 + b2) * weight, fp32 out ----------------
// Same 256x128 / 48KB double-buffer / 3-blocks-per-CU / single-barrier structure.
// Epilogue writes outb (plain stores; atomics measured -30us in r3). 576 blocks fit in
// ONE dispatch round (<=768 resident).

#define KT2 (DH / 32)   // 64 K-tiles

__global__ __launch_bounds__(512, 6) void k_gemm2(const __hip_bfloat16* __restrict__ hid,  // [CAP][DH]
                                                  const __hip_bfloat16* __restrict__ w2T,  // [E][D][H]
                                                  const float* __restrict__ b2,            // [E][D]
                                                  const float* __restrict__ roww,
                                                  const int* __restrict__ offs,
                                                  float* __restrict__ outb) {              // [CAP][DM]
    int bid = blockIdx.x;
    int ib = bid >> 3;
    int row0 = ((bid & 7) * 9 + (ib >> 3)) * 256;
    if (row0 >= offs[NE]) return;
    int d0 = (ib & 7) * 128;
    int e = 0;
    while (row0 >= offs[e + 1]) e++;
    int tid = threadIdx.x;

    __shared__ __align__(16) short lds[2][12288];  // per buffer: A 16KB | B 8KB

    int sr = tid >> 2, pc = tid & 3;
    int ch = pc ^ ((sr >> 1) & 3);
    const short* aS0 = (const short*)hid + (size_t)(row0 + sr) * DH + ch * 8;
    const short* aS1 = (const short*)hid + (size_t)(row0 + 128 + sr) * DH + ch * 8;
    const short* bS  = (const short*)w2T + ((size_t)e * DM + d0 + sr) * DH + ch * 8;
    int ldo = sr * 32 + pc * 8;

    int lane = tid & 63, wv = tid >> 6;
    int wm = (wv >> 1) * 64, wn = (wv & 1) * 64;   // 4M x 2N waves, 64x64 per wave
    int quad = lane >> 4, l16 = lane & 15;
    int a_off[4], b_off[4];
#pragma unroll
    for (int mt = 0; mt < 4; mt++) {
        int r = wm + mt * 16 + l16;
        a_off[mt] = r * 32 + ((quad ^ ((r >> 1) & 3)) * 8);
    }
#pragma unroll
    for (int nt = 0; nt < 4; nt++) {
        int r = wn + nt * 16 + l16;
        b_off[nt] = 8192 + r * 32 + ((quad ^ ((r >> 1) & 3)) * 8);
    }
    float4v acc[4][4];
#pragma unroll
    for (int i = 0; i < 4; i++)
#pragma unroll
        for (int j = 0; j < 4; j++) {
            float4v z = {0.f, 0.f, 0.f, 0.f};
            acc[i][j] = z;
        }

    ASYNC_COPY16(aS0, &lds[0][ldo]);
    ASYNC_COPY16(aS1, &lds[0][4096 + ldo]);
    ASYNC_COPY16(bS,  &lds[0][8192 + ldo]);
    asm volatile("s_waitcnt vmcnt(0)" ::: "memory");
    asm volatile("s_barrier" ::: "memory");

    int buf = 0;
#pragma unroll 1
    for (int t = 0; t < KT2; ++t) {
        const short* Ab = &lds[buf][0];
        int k1 = (t + 1) * 32;
        if (t + 1 < KT2) {
            ASYNC_COPY16(aS0 + k1, &lds[buf ^ 1][ldo]);
            ASYNC_COPY16(aS1 + k1, &lds[buf ^ 1][4096 + ldo]);
            ASYNC_COPY16(bS + k1,  &lds[buf ^ 1][8192 + ldo]);
        }
        short8 af[4], bf[4];
#pragma unroll
        for (int mt = 0; mt < 4; mt++) af[mt] = *(const short8*)(Ab + a_off[mt]);
#pragma unroll
        for (int nt = 0; nt < 4; nt++) bf[nt] = *(const short8*)(Ab + b_off[nt]);
        __builtin_amdgcn_s_setprio(1);
#pragma unroll
        for (int mt = 0; mt < 4; mt++)
#pragma unroll
            for (int nt = 0; nt < 4; nt++)
                acc[mt][nt] = __builtin_amdgcn_mfma_f32_16x16x32_bf16(af[mt], bf[nt], acc[mt][nt], 0, 0, 0);
        __builtin_amdgcn_s_setprio(0);
        asm volatile("s_waitcnt vmcnt(0)" ::: "memory");
        asm volatile("s_barrier" ::: "memory");
        buf ^= 1;
    }

    const float* b2e = b2 + (size_t)e * DM + d0;
#pragma unroll
    for (int mt = 0; mt < 4; mt++) {
#pragma unroll
        for (int nt = 0; nt < 4; nt++) {
            int rl = wm + mt * 16 + quad * 4;
            int cl = wn + nt * 16 + l16;
            float bias = b2e[cl];
#pragma unroll
            for (int r = 0; r < 4; r++) {
                int grow = row0 + rl + r;
                float v = (acc[mt][nt][r] + bias) * roww[grow];
                outb[(size_t)grow * DM + d0 + cl] = v;
            }
        }
    }
}

// ---------------- combine + finalize ----------------

__global__ __launch_bounds__(256) void k_combine(const float* __restrict__ outb,
                                                 const int* __restrict__ slot,
                                                 float* __restrict__ y) {
    int n = blockIdx.x;
    int r0 = slot[2 * n], r1 = slot[2 * n + 1];
    const float4* p0 = (const float4*)(outb + (size_t)r0 * DM);
    const float4* p1 = (const float4*)(outb + (size_t)r1 * DM);
    float4 a = p0[threadIdx.x], b = p1[threadIdx.x];
    float4 c;
    c.x = a.x + b.x;
    c.y = a.y + b.y;
    c.z = a.z + b.z;
    c.w = a.w + b.w;
    ((float4*)(y + (size_t)n * DM))[threadIdx.x] = c;
}

__global__ void k_finalize(const float* __restrict__ fcnt, const float* __restrict__ sump,
                           const float* __restrict__ szent, float* __restrict__ out) {
    if (threadIdx.x == 0 && blockIdx.x == 0) {
        const float invN = 1.0f / (float)NTOK;
        float lb = 0.f;
        float f[NE], P[NE];
        for (int e = 0; e < NE; e++) {
            f[e] = fcnt[e] * invN;
            P[e] = sump[e] * invN;
            lb += f[e] * P[e];
        }
        size_t base = (size_t)NTOK * DM;
        out[base + 0] = -(float)NE * lb;      // lb_loss
        out[base + 1] = szent[0] * invN;      // z_loss
        out[base + 2] = szent[1] * invN;      // entropy
        for (int e = 0; e < NE; e++) out[base + 3 + e] = f[e];
        for (int e = 0; e < NE; e++) out[base + 11 + e] = P[e];
    }
}

// ---------------- launch ----------------

extern "C" void kernel_launch(void* const* d_in, const int* in_sizes, int n_in,
                              void* d_out, int out_size, void* d_ws, size_t ws_size,
                              hipStream_t stream) {
    const float* x  = (const float*)d_in[0];
    const float* rw = (const float*)d_in[1];
    const float* rb = (const float*)d_in[2];
    const float* w1 = (const float*)d_in[3];
    const float* b1 = (const float*)d_in[4];
    const float* w2 = (const float*)d_in[5];
    const float* b2 = (const float*)d_in[6];
    float* out = (float*)d_out;

    char* ws = (char*)d_ws;
    size_t o = 0;
    auto alloc = [&](size_t bytes) {
        size_t r = o;
        o = (o + bytes + 255) & ~(size_t)255;
        return r;
    };
    __hip_bfloat16* w1T = (__hip_bfloat16*)(ws + alloc((size_t)NE * DM * DH * 2));
    __hip_bfloat16* w2T = (__hip_bfloat16*)(ws + alloc((size_t)NE * DM * DH * 2));
    __hip_bfloat16* xb  = (__hip_bfloat16*)(ws + alloc((size_t)NTOK * DM * 2));
    __hip_bfloat16* hid = (__hip_bfloat16*)(ws + alloc((size_t)CAP * DH * 2));
    float* outb = (float*)(ws + alloc((size_t)CAP * DM * 4));
    int* rowtok = (int*)(ws + alloc(CAP * 4));
    size_t zstart = o;
    float* roww  = (float*)(ws + alloc(CAP * 4));
    float* fcnt  = (float*)(ws + alloc(64));
    int* cnt2    = (int*)(ws + alloc(64));
    int* offs    = (int*)(ws + alloc(64));
    float* sump  = (float*)(ws + alloc(64));
    float* szent = (float*)(ws + alloc(64));
    size_t zend = o;
    int* topidx = (int*)(ws + alloc((size_t)NTOK * 2 * 4));
    float* topw = (float*)(ws + alloc((size_t)NTOK * 2 * 4));
    int* slot   = (int*)(ws + alloc((size_t)NTOK * 2 * 4));
    float* probs8 = (float*)(ws + alloc((size_t)NTOK * 8 * 4));
    float* zent   = (float*)(ws + alloc((size_t)NTOK * 2 * 4));

    hipMemsetAsync(rowtok, 0xFF, (size_t)CAP * 4, stream);   // pad rows -> token -1
    hipMemsetAsync(ws + zstart, 0, zend - zstart, stream);   // weights/counters/stats

    k_transpose<<<dim3(DH / 64, DM / 64, NE), 256, 0, stream>>>(w1, w1T, DM, DH);  // -> [E][H][D]
    k_transpose<<<dim3(DM / 64, DH / 64, NE), 256, 0, stream>>>(w2, w2T, DH, DM);  // -> [E][D][H]
    k_router<<<NTOK / 4, 256, 0, stream>>>(x, rw, rb, xb, topidx, topw, probs8, zent);
    k_stats<<<NTOK / 256, 256, 0, stream>>>(topidx, probs8, zent, fcnt, sump, szent);
    k_scan<<<1, 1, 0, stream>>>(fcnt, offs);
    k_scatter<<<NTOK / 256, 256, 0, stream>>>(topidx, topw, offs, cnt2, rowtok, roww, slot);
    k_gemm1<<<1152, 512, 0, stream>>>(xb, w1T, b1, rowtok, offs, hid);  // 72 row x 16 col tiles
    k_gemm2<<<576, 512, 0, stream>>>(hid, w2T, b2, roww, offs, outb);   // 72 row x 8 col tiles
    k_combine<<<NTOK, 256, 0, stream>>>(outb, slot, out);
    k_finalize<<<1, 1, 0, stream>>>(fcnt, sump, szent, out);
}

// Round 5
// 518.583 us; speedup vs baseline: 3.2202x; 3.2202x over previous
//
#include <hip/hip_runtime.h>
#include <hip/hip_bf16.h>

#define NTOK 8192
#define DM 1024
#define NE 8
#define DH 2048
#define CAP 18432   // 16384 + 8*256 padding, multiple of 256 (tiles must not span experts)

typedef __attribute__((ext_vector_type(8))) short short8;
typedef __attribute__((ext_vector_type(4))) float float4v;

// async global->LDS DMA, 16B per lane; LDS dest is wave-uniform base + lane*16
#define ASYNC_COPY16(gsrc, ldst)                                                              \
    __builtin_amdgcn_global_load_lds((const __attribute__((address_space(1))) unsigned int*)(gsrc), \
                                     (__attribute__((address_space(3))) unsigned int*)(ldst), \
                                     16, 0, 0)

static __device__ __forceinline__ unsigned short f2bf(float f) {
    __hip_bfloat16 h = __float2bfloat16(f);
    return *reinterpret_cast<unsigned short*>(&h);
}

// branch-free gelu, exact-erf form via Abramowitz-Stegun 7.1.26 (|err| < 1.5e-7)
static __device__ __forceinline__ float fast_gelu(float v) {
    float x = v * 0.70710678118654752f;
    float ax = fabsf(x);
    float t = __frcp_rn(1.0f + 0.3275911f * ax);
    float poly = ((((1.061405429f * t - 1.453152027f) * t + 1.421413741f) * t
                   - 0.284496736f) * t + 0.254829592f) * t;
    float y = 1.0f - poly * __expf(-ax * ax);   // erf(|x|)
    float erfv = copysignf(y, x);
    return 0.5f * v * (1.0f + erfv);
}

// ---------------- weight transpose: src [z][R][C] fp32 -> dst [z][C][R] bf16 ----------------

__global__ __launch_bounds__(256) void k_transpose(const float* __restrict__ src,
                                                   __hip_bfloat16* __restrict__ dst,
                                                   int R, int C) {
    __shared__ float t[64][65];
    size_t mat = (size_t)blockIdx.z * R * C;
    src += mat;
    dst += mat;
    int c0 = blockIdx.x * 64, r0 = blockIdx.y * 64;
    int tx = threadIdx.x & 63, ty = threadIdx.x >> 6;  // 64 x 4
#pragma unroll
    for (int i = 0; i < 16; i++) {
        int r = ty + i * 4;
        t[r][tx] = src[(size_t)(r0 + r) * C + c0 + tx];
    }
    __syncthreads();
    int rx = (threadIdx.x & 15) * 4;  // 0..60
    int cy = threadIdx.x >> 4;        // 0..15
#pragma unroll
    for (int i = 0; i < 4; i++) {
        int c = cy + i * 16;
        ushort4 v;
        v.x = f2bf(t[rx + 0][c]);
        v.y = f2bf(t[rx + 1][c]);
        v.z = f2bf(t[rx + 2][c]);
        v.w = f2bf(t[rx + 3][c]);
        *(ushort4*)((unsigned short*)dst + (size_t)(c0 + c) * R + r0 + rx) = v;
    }
}

// ---------------- router (atomic-free; also emits xb = bf16(x)) ----------------

__global__ __launch_bounds__(256) void k_router(const float* __restrict__ x,
                                                const float* __restrict__ rw,
                                                const float* __restrict__ rb,
                                                __hip_bfloat16* __restrict__ xb,
                                                int* __restrict__ topidx,
                                                float* __restrict__ topw,
                                                float* __restrict__ probs8,   // [NTOK][8]
                                                float* __restrict__ zent) {   // [NTOK][2]
    int lane = threadIdx.x & 63, wv = threadIdx.x >> 6;
    int n = blockIdx.x * 4 + wv;
    const float* xr = x + (size_t)n * DM;
    unsigned short* xbr = (unsigned short*)xb + (size_t)n * DM;
    float p[8] = {0.f, 0.f, 0.f, 0.f, 0.f, 0.f, 0.f, 0.f};
#pragma unroll
    for (int i = 0; i < 16; i++) {
        int d = lane + i * 64;
        float xv = xr[d];
        xbr[d] = f2bf(xv);
        const float4* w4 = (const float4*)(rw + (size_t)d * 8);
        float4 wa = w4[0], wb = w4[1];
        p[0] += xv * wa.x; p[1] += xv * wa.y; p[2] += xv * wa.z; p[3] += xv * wa.w;
        p[4] += xv * wb.x; p[5] += xv * wb.y; p[6] += xv * wb.z; p[7] += xv * wb.w;
    }
#pragma unroll
    for (int e = 0; e < 8; e++) {
#pragma unroll
        for (int off = 32; off > 0; off >>= 1) p[e] += __shfl_down(p[e], off);
    }
    if (lane == 0) {
        float logits[8], probs[8];
        float mx = -1e30f;
#pragma unroll
        for (int e = 0; e < 8; e++) {
            logits[e] = p[e] + rb[e];
            mx = fmaxf(mx, logits[e]);
        }
        float se = 0.f;
#pragma unroll
        for (int e = 0; e < 8; e++) {
            probs[e] = __expf(logits[e] - mx);
            se += probs[e];
        }
        float inv = 1.f / se;
        float z = mx + logf(se);
        float ent = 0.f;
#pragma unroll
        for (int e = 0; e < 8; e++) {
            probs[e] *= inv;
            ent -= probs[e] * logf(probs[e] + 1e-10f);
        }
        int i0 = 0;
#pragma unroll
        for (int e = 1; e < 8; e++)
            if (probs[e] > probs[i0]) i0 = e;
        int i1 = (i0 == 0) ? 1 : 0;
#pragma unroll
        for (int e = 0; e < 8; e++)
            if (e != i0 && e != i1 && probs[e] > probs[i1]) i1 = e;
        float w0 = probs[i0], w1v = probs[i1];
        float s = w0 + w1v + 1e-9f;
        topidx[2 * n] = i0;
        topidx[2 * n + 1] = i1;
        topw[2 * n] = w0 / s;
        topw[2 * n + 1] = w1v / s;
        float* pr = probs8 + (size_t)n * 8;
#pragma unroll
        for (int e = 0; e < 8; e++) pr[e] = probs[e];
        zent[2 * n] = z * z;
        zent[2 * n + 1] = ent;
    }
}

// ---------------- stats reduction ----------------

__global__ __launch_bounds__(256) void k_stats(const int* __restrict__ topidx,
                                               const float* __restrict__ probs8,
                                               const float* __restrict__ zent,
                                               float* __restrict__ fcnt,
                                               float* __restrict__ sump,
                                               float* __restrict__ szent) {
    int n = blockIdx.x * 256 + threadIdx.x;
    float v[18];
    int e0 = topidx[2 * n], e1 = topidx[2 * n + 1];
#pragma unroll
    for (int e = 0; e < 8; e++) v[e] = (float)((e == e0) + (e == e1));
    const float4* p4 = (const float4*)(probs8 + (size_t)n * 8);
    float4 pa = p4[0], pb = p4[1];
    v[8] = pa.x; v[9] = pa.y; v[10] = pa.z; v[11] = pa.w;
    v[12] = pb.x; v[13] = pb.y; v[14] = pb.z; v[15] = pb.w;
    v[16] = zent[2 * n];
    v[17] = zent[2 * n + 1];
#pragma unroll
    for (int i = 0; i < 18; i++)
#pragma unroll
        for (int off = 32; off > 0; off >>= 1) v[i] += __shfl_down(v[i], off);
    __shared__ float part[4][18];
    int lane = threadIdx.x & 63, wv = threadIdx.x >> 6;
    if (lane == 0)
#pragma unroll
        for (int i = 0; i < 18; i++) part[wv][i] = v[i];
    __syncthreads();
    if (threadIdx.x == 0) {
#pragma unroll
        for (int i = 0; i < 18; i++) {
            float s = part[0][i] + part[1][i] + part[2][i] + part[3][i];
            if (i < 8) atomicAdd(&fcnt[i], s);
            else if (i < 16) atomicAdd(&sump[i - 8], s);
            else atomicAdd(&szent[i - 16], s);
        }
    }
}

// ---------------- scan + scatter ----------------

__global__ void k_scan(const float* __restrict__ fcnt, int* __restrict__ offs) {
    if (threadIdx.x == 0 && blockIdx.x == 0) {
        int o = 0;
        for (int e = 0; e < NE; e++) {
            offs[e] = o;
            int c = (int)(fcnt[e] + 0.5f);
            o += (c + 255) & ~255;   // align 256: GEMM row-tiles (256 rows) never span experts
        }
        offs[NE] = o;
    }
}

__global__ __launch_bounds__(256) void k_scatter(const int* __restrict__ topidx,
                                                 const float* __restrict__ topw,
                                                 const int* __restrict__ offs,
                                                 int* __restrict__ cnt2,
                                                 int* __restrict__ rowtok,
                                                 float* __restrict__ roww,
                                                 int* __restrict__ slot) {
    __shared__ int lcnt[8], lbase[8];
    int tid = threadIdx.x;
    if (tid < 8) lcnt[tid] = 0;
    __syncthreads();
    int n = blockIdx.x * 256 + tid;
    int e0 = topidx[2 * n], e1 = topidx[2 * n + 1];
    int p0 = atomicAdd(&lcnt[e0], 1);
    int p1 = atomicAdd(&lcnt[e1], 1);
    __syncthreads();
    if (tid < 8) lbase[tid] = atomicAdd(&cnt2[tid], lcnt[tid]);
    __syncthreads();
    int r0 = offs[e0] + lbase[e0] + p0;
    int r1 = offs[e1] + lbase[e1] + p1;
    rowtok[r0] = n; roww[r0] = topw[2 * n];     slot[2 * n] = r0;
    rowtok[r1] = n; roww[r1] = topw[2 * n + 1]; slot[2 * n + 1] = r1;
}

// ---------------- GEMM1: hidden = gelu(x_gathered @ w1 + b1), bf16 out ----------------
// m201-style 8-phase schedule: 256x256 tile, BK=64, 8 waves (2Mx4N, 128x64/wave),
// 128KB LDS double-buffer (buf0 = even K-tiles, buf1 = odd). Per K-tile, 4 phases of
// {ds_read subtile || stage 1 half-tile || barrier || lgkmcnt(0) || setprio 16xMFMA || barrier}.
// A-frags held in registers across the K-tile: A-halves free after ph2 (restaged ph3/4),
// B-halves free after ph4 (restaged ph5/6); next buf's A staged ph7/8, B staged ph1/2.
// vmcnt(4) ONLY at phases 4 and 8 -- loads stay 2-4 phases in flight, never drained.
// Ledger (steady, 2 loads/half-tile): ph4-end outstanding = {B(t1) x2, A(tn) x2} + older
//   -> vmcnt(4) lands A(t1)+B(t1) before ph5 reads buf1.  ph8-end outstanding =
//   {A(tn),B(tn), A(tn+1)} -> vmcnt(4) lands all of tn before next-iter ph1 reads buf0.
// Swizzle: 8 chunks/row (64 bf16 = 8x16B), phys = chunk ^ (row&7) -> ds_read_b128
// conflict-free (8 bank-groups x 2 rows); staging pre-swizzles the GLOBAL source, LDS
// dest stays linear (tid*16B), involution verified element-wise.

#define KT1 (DM / 64)   // 16 K-tiles of 64

__global__ __launch_bounds__(512) void k_gemm1(const __hip_bfloat16* __restrict__ xb,
                                               const __hip_bfloat16* __restrict__ w1T,  // [E][H][D]
                                               const float* __restrict__ b1,            // [E][H]
                                               const int* __restrict__ rowtok,
                                               const int* __restrict__ offs,
                                               __hip_bfloat16* __restrict__ hid) {      // [CAP][DH]
    // 576 blocks = 8 XCD x (9 row-tiles x 8 col-tiles), col fastest -> A-tile L2 reuse
    int bid = blockIdx.x;
    int ib = bid >> 3;
    int row0 = ((bid & 7) * 9 + (ib >> 3)) * 256;
    if (row0 >= offs[NE]) return;
    int h0 = (ib & 7) * 256;
    int e = 0;
    while (row0 >= offs[e + 1]) e++;
    int tid = threadIdx.x;

    __shared__ __align__(16) short lds[2][32768];  // 128KB: per buf A[256][64] | B[256][64]
    __shared__ int tokoff[256];
    if (tid < 256) {
        int t = rowtok[row0 + tid];
        tokoff[tid] = (t < 0 ? 0 : t) * DM;  // pad rows compute on token 0 (output unused)
    }
    __syncthreads();
    short* ldsw = &lds[0][0];

    // staging map: tid -> (row = tid>>3 of 64-row sub-block, phys chunk = tid&7)
    int r1 = tid >> 3, pch = tid & 7;
    int lch = pch ^ (r1 & 7);          // logical source chunk (same for row+64/128/192)
    const short* aP00 = (const short*)xb + tokoff[r1] + lch * 8;
    const short* aP01 = (const short*)xb + tokoff[r1 + 64] + lch * 8;
    const short* aP10 = (const short*)xb + tokoff[r1 + 128] + lch * 8;
    const short* aP11 = (const short*)xb + tokoff[r1 + 192] + lch * 8;
    const short* bB   = (const short*)w1T + ((size_t)e * DH + h0) * DM + lch * 8;
    const short* bP00 = bB + (size_t)r1 * DM;
    const short* bP01 = bB + (size_t)(r1 + 64) * DM;
    const short* bP10 = bB + (size_t)(r1 + 128) * DM;
    const short* bP11 = bB + (size_t)(r1 + 192) * DM;

    auto stage2 = [&](const short* s0, const short* s1, int kt, int dstS) {
        ASYNC_COPY16(s0 + kt * 64, ldsw + dstS + tid * 8);
        ASYNC_COPY16(s1 + kt * 64, ldsw + dstS + 4096 + tid * 8);
    };

    int lane = tid & 63, wv = tid >> 6;
    int wm = (wv >> 2) * 128, wn = (wv & 3) * 64;   // 2M x 4N waves, 128x64 per wave
    int quad = lane >> 4, l16 = lane & 15;
    int ba = (wm + l16) * 64;                       // A row base (shorts)
    int bbs = 16384 + (wn + l16) * 64;              // B row base
    int x0 = (quad ^ (l16 & 7)) * 8;                // swizzled k-chunk, kstep 0
    int x1 = ((quad ^ (l16 & 7)) ^ 4) * 8;          // kstep 1
    float4v acc[8][4];
#pragma unroll
    for (int i = 0; i < 8; i++)
#pragma unroll
        for (int j = 0; j < 4; j++) {
            float4v z = {0.f, 0.f, 0.f, 0.f};
            acc[i][j] = z;
        }

    // prologue: K-tile0 full -> buf0 (8 loads), K-tile1 A-halves -> buf1 (4 loads)
    stage2(aP00, aP01, 0, 0);
    stage2(aP10, aP11, 0, 8192);
    stage2(bP00, bP01, 0, 16384);
    stage2(bP10, bP11, 0, 24576);
    stage2(aP00, aP01, 1, 32768);
    stage2(aP10, aP11, 1, 32768 + 8192);
    asm volatile("s_waitcnt vmcnt(4)" ::: "memory");   // K-tile0 landed; K-tile1 A in flight
    asm volatile("s_barrier" ::: "memory");

#define PH_ENTER                                            \
    asm volatile("s_barrier" ::: "memory");                 \
    asm volatile("s_waitcnt lgkmcnt(0)" ::: "memory");      \
    __builtin_amdgcn_sched_barrier(0);                      \
    __builtin_amdgcn_s_setprio(1);
#define PH_EXIT                                             \
    __builtin_amdgcn_s_setprio(0);                          \
    __builtin_amdgcn_sched_barrier(0);                      \
    asm volatile("s_barrier" ::: "memory");

#pragma unroll 1
    for (int it = 0; it < KT1 / 2; ++it) {
        int t1 = 2 * it + 1, tn = 2 * it + 2;
        bool more = tn < KT1;
        short8 a0[8], a1[8], bq0, bq1;

        // ============ K-tile t0 = 2*it (buf0) ============
        {
            const short* pa0 = ldsw + ba + x0;
            const short* pa1 = ldsw + ba + x1;
            const short* pb0 = ldsw + bbs + x0;
            const short* pb1 = ldsw + bbs + x1;
            // phase 1: A k0 (8) + B n0,n1 k0 (2); stage B-h0(t1) -> buf1
#pragma unroll
            for (int mt = 0; mt < 8; mt++) a0[mt] = *(const short8*)(pa0 + mt * 1024);
            bq0 = *(const short8*)(pb0);
            bq1 = *(const short8*)(pb0 + 1024);
            stage2(bP00, bP01, t1, 32768 + 16384);
            PH_ENTER
#pragma unroll
            for (int mt = 0; mt < 8; mt++) {
                acc[mt][0] = __builtin_amdgcn_mfma_f32_16x16x32_bf16(a0[mt], bq0, acc[mt][0], 0, 0, 0);
                acc[mt][1] = __builtin_amdgcn_mfma_f32_16x16x32_bf16(a0[mt], bq1, acc[mt][1], 0, 0, 0);
            }
            PH_EXIT
            // phase 2: A k1 (8) + B n2,n3 k0 (2); stage B-h1(t1) -> buf1
#pragma unroll
            for (int mt = 0; mt < 8; mt++) a1[mt] = *(const short8*)(pa1 + mt * 1024);
            bq0 = *(const short8*)(pb0 + 2048);
            bq1 = *(const short8*)(pb0 + 3072);
            stage2(bP10, bP11, t1, 32768 + 24576);
            PH_ENTER
#pragma unroll
            for (int mt = 0; mt < 8; mt++) {
                acc[mt][2] = __builtin_amdgcn_mfma_f32_16x16x32_bf16(a0[mt], bq0, acc[mt][2], 0, 0, 0);
                acc[mt][3] = __builtin_amdgcn_mfma_f32_16x16x32_bf16(a0[mt], bq1, acc[mt][3], 0, 0, 0);
            }
            PH_EXIT
            // phase 3: B n0,n1 k1 (2); stage A-h0(tn) -> buf0 (A of buf0 free after ph2)
            bq0 = *(const short8*)(pb1);
            bq1 = *(const short8*)(pb1 + 1024);
            if (more) stage2(aP00, aP01, tn, 0);
            PH_ENTER
#pragma unroll
            for (int mt = 0; mt < 8; mt++) {
                acc[mt][0] = __builtin_amdgcn_mfma_f32_16x16x32_bf16(a1[mt], bq0, acc[mt][0], 0, 0, 0);
                acc[mt][1] = __builtin_amdgcn_mfma_f32_16x16x32_bf16(a1[mt], bq1, acc[mt][1], 0, 0, 0);
            }
            PH_EXIT
            // phase 4: B n2,n3 k1 (2); stage A-h1(tn) -> buf0; vmcnt gate for buf1 reads
            bq0 = *(const short8*)(pb1 + 2048);
            bq1 = *(const short8*)(pb1 + 3072);
            if (more) stage2(aP10, aP11, tn, 8192);
            PH_ENTER
#pragma unroll
            for (int mt = 0; mt < 8; mt++) {
                acc[mt][2] = __builtin_amdgcn_mfma_f32_16x16x32_bf16(a1[mt], bq0, acc[mt][2], 0, 0, 0);
                acc[mt][3] = __builtin_amdgcn_mfma_f32_16x16x32_bf16(a1[mt], bq1, acc[mt][3], 0, 0, 0);
            }
            __builtin_amdgcn_s_setprio(0);
            __builtin_amdgcn_sched_barrier(0);
            if (more) asm volatile("s_waitcnt vmcnt(4)" ::: "memory");  // t1 landed; A(tn) flies
            else      asm volatile("s_waitcnt vmcnt(0)" ::: "memory");
            asm volatile("s_barrier" ::: "memory");
        }
        // ============ K-tile t1 (buf1) ============
        {
            const short* pa0 = ldsw + 32768 + ba + x0;
            const short* pa1 = ldsw + 32768 + ba + x1;
            const short* pb0 = ldsw + 32768 + bbs + x0;
            const short* pb1 = ldsw + 32768 + bbs + x1;
            // phase 5: A k0 + B n0,n1 k0; stage B-h0(tn) -> buf0
#pragma unroll
            for (int mt = 0; mt < 8; mt++) a0[mt] = *(const short8*)(pa0 + mt * 1024);
            bq0 = *(const short8*)(pb0);
            bq1 = *(const short8*)(pb0 + 1024);
            if (more) stage2(bP00, bP01, tn, 16384);
            PH_ENTER
#pragma unroll
            for (int mt = 0; mt < 8; mt++) {
                acc[mt][0] = __builtin_amdgcn_mfma_f32_16x16x32_bf16(a0[mt], bq0, acc[mt][0], 0, 0, 0);
                acc[mt][1] = __builtin_amdgcn_mfma_f32_16x16x32_bf16(a0[mt], bq1, acc[mt][1], 0, 0, 0);
            }
            PH_EXIT
            // phase 6: A k1 + B n2,n3 k0; stage B-h1(tn) -> buf0
#pragma unroll
            for (int mt = 0; mt < 8; mt++) a1[mt] = *(const short8*)(pa1 + mt * 1024);
            bq0 = *(const short8*)(pb0 + 2048);
            bq1 = *(const short8*)(pb0 + 3072);
            if (more) stage2(bP10, bP11, tn, 24576);
            PH_ENTER
#pragma unroll
            for (int mt = 0; mt < 8; mt++) {
                acc[mt][2] = __builtin_amdgcn_mfma_f32_16x16x32_bf16(a0[mt], bq0, acc[mt][2], 0, 0, 0);
                acc[mt][3] = __builtin_amdgcn_mfma_f32_16x16x32_bf16(a0[mt], bq1, acc[mt][3], 0, 0, 0);
            }
            PH_EXIT
            // phase 7: B n0,n1 k1; stage A-h0(tn+1) -> buf1
            bq0 = *(const short8*)(pb1);
            bq1 = *(const short8*)(pb1 + 1024);
            if (more) stage2(aP00, aP01, tn + 1, 32768);
            PH_ENTER
#pragma unroll
            for (int mt = 0; mt < 8; mt++) {
                acc[mt][0] = __builtin_amdgcn_mfma_f32_16x16x32_bf16(a1[mt], bq0, acc[mt][0], 0, 0, 0);
                acc[mt][1] = __builtin_amdgcn_mfma_f32_16x16x32_bf16(a1[mt], bq1, acc[mt][1], 0, 0, 0);
            }
            PH_EXIT
            // phase 8: B n2,n3 k1; stage A-h1(tn+1) -> buf1; vmcnt gate for buf0 reads
            bq0 = *(const short8*)(pb1 + 2048);
            bq1 = *(const short8*)(pb1 + 3072);
            if (more) stage2(aP10, aP11, tn + 1, 32768 + 8192);
            PH_ENTER
#pragma unroll
            for (int mt = 0; mt < 8; mt++) {
                acc[mt][2] = __builtin_amdgcn_mfma_f32_16x16x32_bf16(a1[mt], bq0, acc[mt][2], 0, 0, 0);
                acc[mt][3] = __builtin_amdgcn_mfma_f32_16x16x32_bf16(a1[mt], bq1, acc[mt][3], 0, 0, 0);
            }
            __builtin_amdgcn_s_setprio(0);
            __builtin_amdgcn_sched_barrier(0);
            if (more) asm volatile("s_waitcnt vmcnt(4)" ::: "memory");  // tn landed; A(tn+1) flies
            else      asm volatile("s_waitcnt vmcnt(0)" ::: "memory");
            asm volatile("s_barrier" ::: "memory");
        }
    }
#undef PH_ENTER
#undef PH_EXIT

    const float* b1e = b1 + (size_t)e * DH + h0;
#pragma unroll
    for (int mt = 0; mt < 8; mt++) {
#pragma unroll
        for (int nt = 0; nt < 4; nt++) {
            int rl = wm + mt * 16 + quad * 4;
            int cl = wn + nt * 16 + l16;
            float bias = b1e[cl];
#pragma unroll
            for (int r = 0; r < 4; r++) {
                float v = fast_gelu(acc[mt][nt][r] + bias);
                hid[(size_t)(row0 + rl + r) * DH + h0 + cl] = __float2bfloat16(v);
            }
        }
    }
}

// ---------------- GEMM2: outb = (hidden @ w2 + b2) * weight, fp32 out ----------------
// r2 structure verbatim (measured < 141us): 256x128 tile, BK=32, 8 waves (4Mx2N, 64x64),
// triple-buffered 72KB (2 blk/CU), counted vmcnt(3), plain-store epilogue.

#define KT2 (DH / 32)   // 64 K-tiles

__global__ __launch_bounds__(512) void k_gemm2(const __hip_bfloat16* __restrict__ hid,  // [CAP][DH]
                                               const __hip_bfloat16* __restrict__ w2T,  // [E][D][H]
                                               const float* __restrict__ b2,            // [E][D]
                                               const float* __restrict__ roww,
                                               const int* __restrict__ offs,
                                               float* __restrict__ outb) {              // [CAP][DM]
    int bid = blockIdx.x;
    int ib = bid >> 3;
    int row0 = ((bid & 7) * 9 + (ib >> 3)) * 256;
    if (row0 >= offs[NE]) return;
    int d0 = (ib & 7) * 128;
    int e = 0;
    while (row0 >= offs[e + 1]) e++;
    int tid = threadIdx.x;

    __shared__ __align__(16) short lds[3][12288];  // per buffer: A 16KB | B 8KB

    int sr = tid >> 2, pc = tid & 3;
    int ch = pc ^ ((sr >> 1) & 3);
    const short* aS0 = (const short*)hid + (size_t)(row0 + sr) * DH + ch * 8;
    const short* aS1 = (const short*)hid + (size_t)(row0 + 128 + sr) * DH + ch * 8;
    const short* bS  = (const short*)w2T + ((size_t)e * DM + d0 + sr) * DH + ch * 8;
    int ldo = sr * 32 + pc * 8;

    int lane = tid & 63, wv = tid >> 6;
    int wm = (wv >> 1) * 64, wn = (wv & 1) * 64;   // 4M x 2N waves, 64x64 per wave
    int quad = lane >> 4, l16 = lane & 15;
    int a_off[4], b_off[4];
#pragma unroll
    for (int mt = 0; mt < 4; mt++) {
        int r = wm + mt * 16 + l16;
        a_off[mt] = r * 32 + ((quad ^ ((r >> 1) & 3)) * 8);
    }
#pragma unroll
    for (int nt = 0; nt < 4; nt++) {
        int r = wn + nt * 16 + l16;
        b_off[nt] = 8192 + r * 32 + ((quad ^ ((r >> 1) & 3)) * 8);
    }
    float4v acc[4][4];
#pragma unroll
    for (int i = 0; i < 4; i++)
#pragma unroll
        for (int j = 0; j < 4; j++) {
            float4v z = {0.f, 0.f, 0.f, 0.f};
            acc[i][j] = z;
        }

    ASYNC_COPY16(aS0, &lds[0][ldo]);
    ASYNC_COPY16(aS1, &lds[0][4096 + ldo]);
    ASYNC_COPY16(bS,  &lds[0][8192 + ldo]);
    ASYNC_COPY16(aS0 + 32, &lds[1][ldo]);
    ASYNC_COPY16(aS1 + 32, &lds[1][4096 + ldo]);
    ASYNC_COPY16(bS + 32,  &lds[1][8192 + ldo]);
    asm volatile("s_waitcnt vmcnt(3)" ::: "memory");
    asm volatile("s_barrier" ::: "memory");

    int bi = 0;
#pragma unroll 1
    for (int t = 0; t < KT2; ++t) {
        const short* Ab = &lds[bi][0];
        int sbi = bi + 2; if (sbi >= 3) sbi -= 3;
        int k2 = (t + 2) * 32;
        short8 af[4], bf[4];
#pragma unroll
        for (int mt = 0; mt < 4; mt++) af[mt] = *(const short8*)(Ab + a_off[mt]);
#pragma unroll
        for (int nt = 0; nt < 4; nt++) bf[nt] = *(const short8*)(Ab + b_off[nt]);
        if (t + 2 < KT2) {
            ASYNC_COPY16(aS0 + k2, &lds[sbi][ldo]);
            ASYNC_COPY16(aS1 + k2, &lds[sbi][4096 + ldo]);
            ASYNC_COPY16(bS + k2,  &lds[sbi][8192 + ldo]);
        }
        asm volatile("s_barrier" ::: "memory");
        __builtin_amdgcn_sched_barrier(0);
        __builtin_amdgcn_s_setprio(1);
#pragma unroll
        for (int mt = 0; mt < 4; mt++)
#pragma unroll
            for (int nt = 0; nt < 4; nt++)
                acc[mt][nt] = __builtin_amdgcn_mfma_f32_16x16x32_bf16(af[mt], bf[nt], acc[mt][nt], 0, 0, 0);
        __builtin_amdgcn_s_setprio(0);
        __builtin_amdgcn_sched_barrier(0);
        if (t + 2 < KT2) asm volatile("s_waitcnt vmcnt(3)" ::: "memory");
        else             asm volatile("s_waitcnt vmcnt(0)" ::: "memory");
        asm volatile("s_barrier" ::: "memory");
        bi++; if (bi == 3) bi = 0;
    }

    const float* b2e = b2 + (size_t)e * DM + d0;
#pragma unroll
    for (int mt = 0; mt < 4; mt++) {
#pragma unroll
        for (int nt = 0; nt < 4; nt++) {
            int rl = wm + mt * 16 + quad * 4;
            int cl = wn + nt * 16 + l16;
            float bias = b2e[cl];
#pragma unroll
            for (int r = 0; r < 4; r++) {
                int grow = row0 + rl + r;
                float v = (acc[mt][nt][r] + bias) * roww[grow];
                outb[(size_t)grow * DM + d0 + cl] = v;
            }
        }
    }
}

// ---------------- combine + finalize ----------------

__global__ __launch_bounds__(256) void k_combine(const float* __restrict__ outb,
                                                 const int* __restrict__ slot,
                                                 float* __restrict__ y) {
    int n = blockIdx.x;
    int r0 = slot[2 * n], r1 = slot[2 * n + 1];
    const float4* p0 = (const float4*)(outb + (size_t)r0 * DM);
    const float4* p1 = (const float4*)(outb + (size_t)r1 * DM);
    float4 a = p0[threadIdx.x], b = p1[threadIdx.x];
    float4 c;
    c.x = a.x + b.x;
    c.y = a.y + b.y;
    c.z = a.z + b.z;
    c.w = a.w + b.w;
    ((float4*)(y + (size_t)n * DM))[threadIdx.x] = c;
}

__global__ void k_finalize(const float* __restrict__ fcnt, const float* __restrict__ sump,
                           const float* __restrict__ szent, float* __restrict__ out) {
    if (threadIdx.x == 0 && blockIdx.x == 0) {
        const float invN = 1.0f / (float)NTOK;
        float lb = 0.f;
        float f[NE], P[NE];
        for (int e = 0; e < NE; e++) {
            f[e] = fcnt[e] * invN;
            P[e] = sump[e] * invN;
            lb += f[e] * P[e];
        }
        size_t base = (size_t)NTOK * DM;
        out[base + 0] = -(float)NE * lb;      // lb_loss
        out[base + 1] = szent[0] * invN;      // z_loss
        out[base + 2] = szent[1] * invN;      // entropy
        for (int e = 0; e < NE; e++) out[base + 3 + e] = f[e];
        for (int e = 0; e < NE; e++) out[base + 11 + e] = P[e];
    }
}

// ---------------- launch ----------------

extern "C" void kernel_launch(void* const* d_in, const int* in_sizes, int n_in,
                              void* d_out, int out_size, void* d_ws, size_t ws_size,
                              hipStream_t stream) {
    const float* x  = (const float*)d_in[0];
    const float* rw = (const float*)d_in[1];
    const float* rb = (const float*)d_in[2];
    const float* w1 = (const float*)d_in[3];
    const float* b1 = (const float*)d_in[4];
    const float* w2 = (const float*)d_in[5];
    const float* b2 = (const float*)d_in[6];
    float* out = (float*)d_out;

    char* ws = (char*)d_ws;
    size_t o = 0;
    auto alloc = [&](size_t bytes) {
        size_t r = o;
        o = (o + bytes + 255) & ~(size_t)255;
        return r;
    };
    __hip_bfloat16* w1T = (__hip_bfloat16*)(ws + alloc((size_t)NE * DM * DH * 2));
    __hip_bfloat16* w2T = (__hip_bfloat16*)(ws + alloc((size_t)NE * DM * DH * 2));
    __hip_bfloat16* xb  = (__hip_bfloat16*)(ws + alloc((size_t)NTOK * DM * 2));
    __hip_bfloat16* hid = (__hip_bfloat16*)(ws + alloc((size_t)CAP * DH * 2));
    float* outb = (float*)(ws + alloc((size_t)CAP * DM * 4));
    int* rowtok = (int*)(ws + alloc(CAP * 4));
    size_t zstart = o;
    float* roww  = (float*)(ws + alloc(CAP * 4));
    float* fcnt  = (float*)(ws + alloc(64));
    int* cnt2    = (int*)(ws + alloc(64));
    int* offs    = (int*)(ws + alloc(64));
    float* sump  = (float*)(ws + alloc(64));
    float* szent = (float*)(ws + alloc(64));
    size_t zend = o;
    int* topidx = (int*)(ws + alloc((size_t)NTOK * 2 * 4));
    float* topw = (float*)(ws + alloc((size_t)NTOK * 2 * 4));
    int* slot   = (int*)(ws + alloc((size_t)NTOK * 2 * 4));
    float* probs8 = (float*)(ws + alloc((size_t)NTOK * 8 * 4));
    float* zent   = (float*)(ws + alloc((size_t)NTOK * 2 * 4));

    hipMemsetAsync(rowtok, 0xFF, (size_t)CAP * 4, stream);   // pad rows -> token -1
    hipMemsetAsync(ws + zstart, 0, zend - zstart, stream);   // weights/counters/stats

    k_transpose<<<dim3(DH / 64, DM / 64, NE), 256, 0, stream>>>(w1, w1T, DM, DH);  // -> [E][H][D]
    k_transpose<<<dim3(DM / 64, DH / 64, NE), 256, 0, stream>>>(w2, w2T, DH, DM);  // -> [E][D][H]
    k_router<<<NTOK / 4, 256, 0, stream>>>(x, rw, rb, xb, topidx, topw, probs8, zent);
    k_stats<<<NTOK / 256, 256, 0, stream>>>(topidx, probs8, zent, fcnt, sump, szent);
    k_scan<<<1, 1, 0, stream>>>(fcnt, offs);
    k_scatter<<<NTOK / 256, 256, 0, stream>>>(topidx, topw, offs, cnt2, rowtok, roww, slot);
    k_gemm1<<<576, 512, 0, stream>>>(xb, w1T, b1, rowtok, offs, hid);   // 72 row x 8 col tiles
    k_gemm2<<<576, 512, 0, stream>>>(hid, w2T, b2, roww, offs, outb);   // 72 row x 8 col tiles
    k_combine<<<NTOK, 256, 0, stream>>>(outb, slot, out);
    k_finalize<<<1, 1, 0, stream>>>(fcnt, sump, szent, out);
}